// Round 5
// baseline (3178.129 us; speedup 1.0000x reference)
//
#include <hip/hip_runtime.h>
#include <cstdint>

#define Bb 64
#define Tt 4096
#define Dd 67
#define Hh 128
#define CH 16            // scan z-chunk: 16 steps x 512 n x 2B = 16 KB
#define NCH (Tt/CH)

typedef _Float16 f16;
typedef _Float16 half8 __attribute__((ext_vector_type(8)));
typedef float f32x4 __attribute__((ext_vector_type(4)));

#define MFMA16(A,B,C) __builtin_amdgcn_mfma_f32_16x16x32_f16((A),(B),(C),0,0,0)

static __device__ __forceinline__ float fast_rcp(float x){ return __builtin_amdgcn_rcpf(x); }
static __device__ __forceinline__ float fast_ex2(float x){ return __builtin_amdgcn_exp2f(x); }
static __device__ __forceinline__ float rlane(float v, int l){
  return __builtin_bit_cast(float, __builtin_amdgcn_readlane(__builtin_bit_cast(int, v), l));
}
#define L2E  1.442695041f
#define L2E2 2.885390082f

union U2 { uint2 u; f16 h[4]; };
union U1 { unsigned u; f16 h[2]; };

__device__ __forceinline__ void red2(float& s, float& q){
#pragma unroll
  for (int off = 32; off; off >>= 1){ s += __shfl_xor(s, off); q += __shfl_xor(q, off); }
}

// ---------------------------------------------------------------------------
// Stage A: LN(67) -> MFMA proj -> LN(128)+SiLU -> MFMA GEMM2 -> z fp16 to
// d_ws in [b][t][j*4+g] layout (gate-packed per row: scan reads 1 b64/tile).
// ---------------------------------------------------------------------------
__global__ __launch_bounds__(512, 2)
void stage_a(const float* __restrict__ x,
             const float* __restrict__ g_in, const float* __restrict__ b_in,
             const float* __restrict__ proj_w, const float* __restrict__ proj_b,
             const float* __restrict__ g_p, const float* __restrict__ b_p,
             const float* __restrict__ w_ff1, const float* __restrict__ bi_ff1,
             const float* __restrict__ w_ff2, const float* __restrict__ bi_ff2,
             const float* __restrict__ w_ta,  const float* __restrict__ bi_ta,
             const float* __restrict__ w_tb,  const float* __restrict__ bi_tb,
             f16* __restrict__ zx)
{
  __shared__ __align__(16) f16   xn_s[16*104];
  __shared__ __align__(16) float fpre_s[16*132];
  __shared__ __align__(16) f16   feat_s[16*136];

  const int tid  = threadIdx.x;
  const int wv   = tid >> 6;
  const int lane = tid & 63;
  const int q    = lane >> 4;
  const int l16  = lane & 15;
  const int jq   = 16*wv + 4*q;

  const float* Wg[4] = { w_ff1, w_ff2, w_ta, w_tb };
  const float* Bg[4] = { bi_ff1, bi_ff2, bi_ta, bi_tb };

  half8 aW1[3];
#pragma unroll
  for (int c = 0; c < 3; ++c)
#pragma unroll
    for (int i = 0; i < 8; ++i){
      int k = 32*c + 8*q + i;
      aW1[c][i] = (k < Dd) ? (f16)proj_w[k*Hh + (16*wv + l16)] : (f16)0.f;
    }
  half8 aW2[4][4];
  f32x4 bias2[4];
#pragma unroll
  for (int g = 0; g < 4; ++g){
    const float* wp = Wg[g];
    const int jc = 16*wv + l16;
#pragma unroll
    for (int c = 0; c < 4; ++c)
#pragma unroll
      for (int i = 0; i < 8; ++i){
        int k = 32*c + 8*q + i;
        aW2[g][c][i] = (f16)wp[k*Hh + jc];
      }
    bias2[g] = *(const f32x4*)(Bg[g] + jq);
  }
  const float gi0 = g_in[lane], bi0 = b_in[lane];
  const float gi1 = (lane < 3) ? g_in[64+lane] : 0.f;
  const float bi1 = (lane < 3) ? b_in[64+lane] : 0.f;
  const float gp0 = g_p[lane],  bp0 = b_p[lane];
  const float gp1 = g_p[64+lane], bp1 = b_p[64+lane];
  const float pb0 = proj_b[lane], pb1 = proj_b[64+lane];

  for (int idx = tid; idx < 16*104; idx += 512)
    if ((idx % 104) >= Dd) xn_s[idx] = (f16)0.f;
  __syncthreads();

  const int wg   = blockIdx.x;
  const int b    = wg >> 2;
  const int t0wg = (wg & 3) * 1024;

  for (int it = 0; it < 64; ++it){
    const int tl0 = t0wg + it*16;
#pragma unroll
    for (int hf = 0; hf < 2; ++hf){
      const int ts = wv + 8*hf;
      const float* xr = x + (size_t)(b*Tt + tl0 + ts) * Dd;
      float v0 = xr[lane];
      float v1 = (lane < 3) ? xr[64+lane] : 0.f;
      float s = v0 + v1, qq = v0*v0 + v1*v1;
      red2(s, qq);
      float mu = s * (1.0f/Dd);
      float rstd = rsqrtf(qq * (1.0f/Dd) - mu*mu + 1e-5f);
      xn_s[ts*104 + lane] = (f16)((v0 - mu)*rstd*gi0 + bi0);
      if (lane < 3) xn_s[ts*104 + 64 + lane] = (f16)((v1 - mu)*rstd*gi1 + bi1);
    }
    __syncthreads();
    {
      f32x4 acc = {0.f, 0.f, 0.f, 0.f};
#pragma unroll
      for (int c = 0; c < 3; ++c){
        half8 bf = *(const half8*)(xn_s + l16*104 + 32*c + 8*q);
        acc = MFMA16(aW1[c], bf, acc);
      }
      *(f32x4*)(fpre_s + l16*132 + jq) = acc;
    }
    __syncthreads();
#pragma unroll
    for (int hf = 0; hf < 2; ++hf){
      const int ts = wv + 8*hf;
      float v0 = fpre_s[ts*132 + lane]      + pb0;
      float v1 = fpre_s[ts*132 + 64 + lane] + pb1;
      float s = v0 + v1, qq = v0*v0 + v1*v1;
      red2(s, qq);
      float mu = s * (1.0f/Hh);
      float rstd = rsqrtf(qq * (1.0f/Hh) - mu*mu + 1e-5f);
      float f0 = (v0 - mu)*rstd*gp0 + bp0;
      float f1 = (v1 - mu)*rstd*gp1 + bp1;
      f0 *= fast_rcp(1.0f + fast_ex2(-L2E*f0));
      f1 *= fast_rcp(1.0f + fast_ex2(-L2E*f1));
      feat_s[ts*136 + lane]      = (f16)f0;
      feat_s[ts*136 + 64 + lane] = (f16)f1;
    }
    __syncthreads();
    {
      half8 bf2[4];
#pragma unroll
      for (int c = 0; c < 4; ++c)
        bf2[c] = *(const half8*)(feat_s + l16*136 + 32*c + 8*q);
      const size_t trow = (size_t)(b*Tt + tl0 + l16) * 512;
      f32x4 accs2[4];
#pragma unroll
      for (int g = 0; g < 4; ++g){
        f32x4 acc = bias2[g];
#pragma unroll
        for (int c = 0; c < 4; ++c)
          acc = MFMA16(aW2[g][c], bf2[c], acc);
        accs2[g] = acc;
      }
      // gate-packed store: [t][j*4+g]
#pragma unroll
      for (int r = 0; r < 4; ++r){
        U2 u;
#pragma unroll
        for (int g = 0; g < 4; ++g) u.h[g] = (f16)accs2[g][r];
        *(uint2*)(zx + trow + (size_t)(jq + r)*4) = u.u;
      }
    }
    __syncthreads();
  }
}

// ---------------------------------------------------------------------------
// Scan v5: 64 WGs x 256 thr (4 waves; wave wv owns j-tiles wv and wv+4).
// Per step/CU LDS ops: 16 b128 (h bcast) + 8 b64 (z) + 8 b16 (h write) — no
// shuffles, no dt reads. h history kept in a 16-slot LDS ring, dumped per
// chunk into the consumed z region of d_ws; head done by head_k afterwards.
// ---------------------------------------------------------------------------
__global__ __launch_bounds__(256, 1)
void scan_k(f16* __restrict__ zx, const float* __restrict__ dt,
            const float* __restrict__ w_ff1, const float* __restrict__ w_ff2,
            const float* __restrict__ w_ta,  const float* __restrict__ w_tb)
{
  __shared__ __align__(16) f16 zbuf[2][CH*512];  // 2 x 16 KB
  __shared__ __align__(16) f16 hist[CH][Hh];     // 4 KB ring of h

  const int tid  = threadIdx.x;
  const int wv   = tid >> 6;        // 0..3
  const int lane = tid & 63;
  const int q    = lane >> 4;
  const int l16  = lane & 15;
  const int rr   = l16 & 3;
  const bool sel1 = (rr & 1) != 0;
  const bool sel2 = (rr & 2) != 0;
  const int b    = blockIdx.x;

  const int j0 = 16*wv + 4*q + rr;  // own rows (tile0, tile1 = +64)

  const float* Wg[4] = { w_ff1, w_ff2, w_ta, w_tb };
  half8 aW[2][4][4];                // W_bot^T: [tile][gate][kchunk]
#pragma unroll
  for (int tl = 0; tl < 2; ++tl){
    const int jc = 16*wv + 64*tl + l16;
#pragma unroll
    for (int g = 0; g < 4; ++g){
      const float* wp = Wg[g];
#pragma unroll
      for (int c = 0; c < 4; ++c)
#pragma unroll
        for (int i = 0; i < 8; ++i)
          aW[tl][g][c][i] = (f16)wp[(128 + 32*c + 8*q + i)*Hh + jc];
    }
  }

  // zero hist ring (slot 15 must be 0 for t=0; zero all)
  ((float4*)hist)[tid] = make_float4(0.f, 0.f, 0.f, 0.f);

  f16* zg = zx + (size_t)b*Tt*512;
  const float4* zg4 = (const float4*)zg;         // chunk = 1024 float4

  // prologue: chunk0 -> regs -> zbuf[0]; chunk1 -> regs; dt chunk0 -> reg
  float4 rz[4];
#pragma unroll
  for (int j = 0; j < 4; ++j) rz[j] = zg4[j*256 + tid];
#pragma unroll
  for (int j = 0; j < 4; ++j) ((float4*)zbuf[0])[j*256 + tid] = rz[j];
#pragma unroll
  for (int j = 0; j < 4; ++j) rz[j] = zg4[1024 + j*256 + tid];
  float dtcur = dt[(size_t)b*Tt + l16] * 10.0f;
  __syncthreads();

  for (int c = 0; c < NCH; ++c){
    const int cur = c & 1, nxt = cur ^ 1;
    // commit staged regs (chunk c+1) to zbuf[nxt]; refill with chunk c+2
#pragma unroll
    for (int j = 0; j < 4; ++j) ((float4*)zbuf[nxt])[j*256 + tid] = rz[j];
    if (c + 2 < NCH){
      const float4* src = zg4 + (size_t)(c+2)*1024;
#pragma unroll
      for (int j = 0; j < 4; ++j) rz[j] = src[j*256 + tid];
    }
    float dtnxt = dtcur;
    if (c + 1 < NCH) dtnxt = dt[(size_t)b*Tt + (c+1)*CH + l16] * 10.0f;

    for (int s = 0; s < CH; ++s){
      const int slotR = (s + 15) & 15;
      // h fragments: full 128 h, broadcast b128 x4
      half8 bf[4];
#pragma unroll
      for (int cc = 0; cc < 4; ++cc)
        bf[cc] = *(const half8*)(&hist[slotR][32*cc + 8*q]);
      // z: gate-packed b64 per tile
      const f16* zp = &zbuf[cur][s*512];
      U2 z0, z1;
      z0.u = *(const uint2*)(zp + 4*j0);
      z1.u = *(const uint2*)(zp + 4*(j0+64));
      const float dtt = rlane(dtcur, s);

      f32x4 accs[2][4];
#pragma unroll
      for (int tl = 0; tl < 2; ++tl)
#pragma unroll
        for (int g = 0; g < 4; ++g){
          f32x4 a = {0.f, 0.f, 0.f, 0.f};
#pragma unroll
          for (int cc = 0; cc < 4; ++cc)
            a = MFMA16(aW[tl][g][cc], bf[cc], a);
          accs[tl][g] = a;
        }
      // select own r, add z, CfC cell — per tile
      f16 hn01[2];
#pragma unroll
      for (int tl = 0; tl < 2; ++tl){
        float pre[4];
        U2 zz = tl ? z1 : z0;
#pragma unroll
        for (int g = 0; g < 4; ++g){
          float s01 = sel1 ? accs[tl][g][1] : accs[tl][g][0];
          float s23 = sel1 ? accs[tl][g][3] : accs[tl][g][2];
          pre[g] = (sel2 ? s23 : s01) + (float)zz.h[g];
        }
        float u_ = fast_rcp(fast_ex2(L2E2*pre[0]) + 1.0f);   // (1-tanh)/2
        float v_ = fast_rcp(fast_ex2(L2E2*pre[1]) + 1.0f);
        float g_ = fast_rcp(fast_ex2(-L2E*(pre[2]*dtt + pre[3])) + 1.0f);
        hn01[tl] = (f16)(1.0f - 2.0f*(u_ - g_*(u_ - v_)));
      }
      if (l16 < 4){                   // l16 == rr here; distinct j per lane
        hist[s][j0]      = hn01[0];
        hist[s][j0 + 64] = hn01[1];
      }
      __syncthreads();
    }
    // dump h ring into the consumed z region: h[t] -> zg[t*512 + 0..127]
    {
      const float4 hv = ((const float4*)hist)[tid];   // slot=tid>>4, frag=tid&15
      *(float4*)(zg + ((size_t)(c*CH + (tid >> 4)))*512 + (size_t)(tid & 15)*8) = hv;
    }
    __syncthreads();                  // protect hist reuse next chunk
    dtcur = dtnxt;
  }
}

// ---------------------------------------------------------------------------
// Head: out[tok] = h[tok] . head_w + head_b. One wave per token; h fp16 from
// the dumped region (first 128 halves of each 512-half slot).
// ---------------------------------------------------------------------------
__global__ __launch_bounds__(256, 4)
void head_k(const f16* __restrict__ zx, const float* __restrict__ head_w,
            const float* __restrict__ head_b, float* __restrict__ out)
{
  const int tok  = (blockIdx.x << 2) + (threadIdx.x >> 6);
  const int lane = threadIdx.x & 63;
  U1 cv; cv.u = *(const unsigned*)(zx + (size_t)tok*512 + 2*lane);
  float s = (float)cv.h[0]*head_w[2*lane] + (float)cv.h[1]*head_w[2*lane+1];
#pragma unroll
  for (int off = 32; off; off >>= 1) s += __shfl_xor(s, off);
  if (lane == 0) out[tok] = s + head_b[0];
}

extern "C" void kernel_launch(void* const* d_in, const int* in_sizes, int n_in,
                              void* d_out, int out_size, void* d_ws, size_t ws_size,
                              hipStream_t stream)
{
  const float* x       = (const float*)d_in[0];
  const float* dt      = (const float*)d_in[1];
  const float* ln_in_g = (const float*)d_in[2];
  const float* ln_in_b = (const float*)d_in[3];
  const float* proj_w  = (const float*)d_in[4];
  const float* proj_b  = (const float*)d_in[5];
  const float* ln_p_g  = (const float*)d_in[6];
  const float* ln_p_b  = (const float*)d_in[7];
  const float* ff1_w   = (const float*)d_in[8];
  const float* ff1_b   = (const float*)d_in[9];
  const float* ff2_w   = (const float*)d_in[10];
  const float* ff2_b   = (const float*)d_in[11];
  const float* ta_w    = (const float*)d_in[12];
  const float* ta_b    = (const float*)d_in[13];
  const float* tb_w    = (const float*)d_in[14];
  const float* tb_b    = (const float*)d_in[15];
  const float* head_w  = (const float*)d_in[16];
  const float* head_b  = (const float*)d_in[17];

  f16*   zx  = (f16*)d_ws;      // [b][t][512] fp16 = 256 MiB (z, then h)
  float* out = (float*)d_out;

  stage_a<<<dim3(256), dim3(512), 0, stream>>>(
      x, ln_in_g, ln_in_b, proj_w, proj_b, ln_p_g, ln_p_b,
      ff1_w, ff1_b, ff2_w, ff2_b, ta_w, ta_b, tb_w, tb_b, zx);

  scan_k<<<dim3(Bb), dim3(256), 0, stream>>>(
      zx, dt, ff1_w, ff2_w, ta_w, tb_w);

  head_k<<<dim3(Bb*Tt/4), dim3(256), 0, stream>>>(
      zx, head_w, head_b, out);
}

// Round 6
// 2903.432 us; speedup vs baseline: 1.0946x; 1.0946x over previous
//
#include <hip/hip_runtime.h>
#include <cstdint>

#define Bb 64
#define Tt 4096
#define Dd 67
#define Hh 128
#define CH 16            // scan z-chunk: 16 steps x 512 n x 2B = 16 KB
#define NCH (Tt/CH)

typedef _Float16 f16;
typedef _Float16 half8 __attribute__((ext_vector_type(8)));
typedef float f32x4 __attribute__((ext_vector_type(4)));

#define MFMA16(A,B,C) __builtin_amdgcn_mfma_f32_16x16x32_f16((A),(B),(C),0,0,0)

static __device__ __forceinline__ float fast_rcp(float x){ return __builtin_amdgcn_rcpf(x); }
static __device__ __forceinline__ float fast_ex2(float x){ return __builtin_amdgcn_exp2f(x); }
static __device__ __forceinline__ float rlane(float v, int l){
  return __builtin_bit_cast(float, __builtin_amdgcn_readlane(__builtin_bit_cast(int, v), l));
}
#define L2E  1.442695041f
#define L2E2 2.885390082f

union U2 { uint2 u; f16 h[4]; };
union U1 { unsigned u; f16 h[2]; };

__device__ __forceinline__ void red2(float& s, float& q){
#pragma unroll
  for (int off = 32; off; off >>= 1){ s += __shfl_xor(s, off); q += __shfl_xor(q, off); }
}

// ---------------------------------------------------------------------------
// Stage A: LN(67) -> MFMA proj -> LN(128)+SiLU -> MFMA GEMM2 -> z fp16 to
// d_ws in scan layout [b][t][w(4)][l16(16)][(s,g)(8)]  (1 b128/lane in scan).
// ---------------------------------------------------------------------------
__global__ __launch_bounds__(512, 2)
void stage_a(const float* __restrict__ x,
             const float* __restrict__ g_in, const float* __restrict__ b_in,
             const float* __restrict__ proj_w, const float* __restrict__ proj_b,
             const float* __restrict__ g_p, const float* __restrict__ b_p,
             const float* __restrict__ w_ff1, const float* __restrict__ bi_ff1,
             const float* __restrict__ w_ff2, const float* __restrict__ bi_ff2,
             const float* __restrict__ w_ta,  const float* __restrict__ bi_ta,
             const float* __restrict__ w_tb,  const float* __restrict__ bi_tb,
             f16* __restrict__ zx)
{
  __shared__ __align__(16) f16   xn_s[16*104];
  __shared__ __align__(16) float fpre_s[16*132];
  __shared__ __align__(16) f16   feat_s[16*136];

  const int tid  = threadIdx.x;
  const int wv   = tid >> 6;
  const int lane = tid & 63;
  const int q    = lane >> 4;
  const int l16  = lane & 15;
  const int jq   = 16*wv + 4*q;

  const float* Wg[4] = { w_ff1, w_ff2, w_ta, w_tb };
  const float* Bg[4] = { bi_ff1, bi_ff2, bi_ta, bi_tb };

  half8 aW1[3];
#pragma unroll
  for (int c = 0; c < 3; ++c)
#pragma unroll
    for (int i = 0; i < 8; ++i){
      int k = 32*c + 8*q + i;
      aW1[c][i] = (k < Dd) ? (f16)proj_w[k*Hh + (16*wv + l16)] : (f16)0.f;
    }
  half8 aW2[4][4];
  f32x4 bias2[4];
#pragma unroll
  for (int g = 0; g < 4; ++g){
    const float* wp = Wg[g];
    const int jc = 16*wv + l16;
#pragma unroll
    for (int c = 0; c < 4; ++c)
#pragma unroll
      for (int i = 0; i < 8; ++i){
        int k = 32*c + 8*q + i;
        aW2[g][c][i] = (f16)wp[k*Hh + jc];
      }
    bias2[g] = *(const f32x4*)(Bg[g] + jq);
  }
  const float gi0 = g_in[lane], bi0 = b_in[lane];
  const float gi1 = (lane < 3) ? g_in[64+lane] : 0.f;
  const float bi1 = (lane < 3) ? b_in[64+lane] : 0.f;
  const float gp0 = g_p[lane],  bp0 = b_p[lane];
  const float gp1 = g_p[64+lane], bp1 = b_p[64+lane];
  const float pb0 = proj_b[lane], pb1 = proj_b[64+lane];

  for (int idx = tid; idx < 16*104; idx += 512)
    if ((idx % 104) >= Dd) xn_s[idx] = (f16)0.f;
  __syncthreads();

  const int wg   = blockIdx.x;
  const int b    = wg >> 2;
  const int t0wg = (wg & 3) * 1024;

  for (int it = 0; it < 64; ++it){
    const int tl0 = t0wg + it*16;
#pragma unroll
    for (int hf = 0; hf < 2; ++hf){
      const int ts = wv + 8*hf;
      const float* xr = x + (size_t)(b*Tt + tl0 + ts) * Dd;
      float v0 = xr[lane];
      float v1 = (lane < 3) ? xr[64+lane] : 0.f;
      float s = v0 + v1, qq = v0*v0 + v1*v1;
      red2(s, qq);
      float mu = s * (1.0f/Dd);
      float rstd = rsqrtf(qq * (1.0f/Dd) - mu*mu + 1e-5f);
      xn_s[ts*104 + lane] = (f16)((v0 - mu)*rstd*gi0 + bi0);
      if (lane < 3) xn_s[ts*104 + 64 + lane] = (f16)((v1 - mu)*rstd*gi1 + bi1);
    }
    __syncthreads();
    {
      f32x4 acc = {0.f, 0.f, 0.f, 0.f};
#pragma unroll
      for (int c = 0; c < 3; ++c){
        half8 bf = *(const half8*)(xn_s + l16*104 + 32*c + 8*q);
        acc = MFMA16(aW1[c], bf, acc);
      }
      *(f32x4*)(fpre_s + l16*132 + jq) = acc;
    }
    __syncthreads();
#pragma unroll
    for (int hf = 0; hf < 2; ++hf){
      const int ts = wv + 8*hf;
      float v0 = fpre_s[ts*132 + lane]      + pb0;
      float v1 = fpre_s[ts*132 + 64 + lane] + pb1;
      float s = v0 + v1, qq = v0*v0 + v1*v1;
      red2(s, qq);
      float mu = s * (1.0f/Hh);
      float rstd = rsqrtf(qq * (1.0f/Hh) - mu*mu + 1e-5f);
      float f0 = (v0 - mu)*rstd*gp0 + bp0;
      float f1 = (v1 - mu)*rstd*gp1 + bp1;
      f0 *= fast_rcp(1.0f + fast_ex2(-L2E*f0));
      f1 *= fast_rcp(1.0f + fast_ex2(-L2E*f1));
      feat_s[ts*136 + lane]      = (f16)f0;
      feat_s[ts*136 + 64 + lane] = (f16)f1;
    }
    __syncthreads();
    {
      half8 bf2[4];
#pragma unroll
      for (int c = 0; c < 4; ++c)
        bf2[c] = *(const half8*)(feat_s + l16*136 + 32*c + 8*q);
      const size_t trow = (size_t)(b*Tt + tl0 + l16) * 512;
      f32x4 accs2[4];
#pragma unroll
      for (int g = 0; g < 4; ++g){
        f32x4 acc = bias2[g];
#pragma unroll
        for (int c = 0; c < 4; ++c)
          acc = MFMA16(aW2[g][c], bf2[c], acc);
        accs2[g] = acc;
      }
      // scan layout store: j = 16wv+4q+r -> [w=wv>>1][l=4q+r][s=wv&1][g]
#pragma unroll
      for (int r = 0; r < 4; ++r){
        U2 u;
#pragma unroll
        for (int g = 0; g < 4; ++g) u.h[g] = (f16)accs2[g][r];
        const int zoff = ((wv>>1)*128) + ((4*q + r)*8) + ((wv&1)*4);
        *(uint2*)(zx + trow + zoff) = u.u;
      }
    }
    __syncthreads();
  }
}

// ---------------------------------------------------------------------------
// Scan v6: 64 WGs x 256 thr. Transposed MFMA: h = A operand (M-rows dup),
// weights = B operand (VGPR-resident) -> output n on lane dim, NO row-select.
// K split 2+2 (16 indep depth-2 chains). z: 1 b128/lane. Cell dedup across q
// (q<2 -> s=0, q>=2 -> s=1). h ring -> chunk dump -> head_k.
// ---------------------------------------------------------------------------
__global__ __launch_bounds__(256, 1)
void scan_k(f16* __restrict__ zx, const float* __restrict__ dt,
            const float* __restrict__ w_ff1, const float* __restrict__ w_ff2,
            const float* __restrict__ w_ta,  const float* __restrict__ w_tb)
{
  __shared__ __align__(16) f16 zbuf[2][CH*512];  // 2 x 16 KB
  __shared__ __align__(16) f16 hist[CH][Hh];     // 4 KB ring of h

  const int tid  = threadIdx.x;
  const int wv   = tid >> 6;        // 0..3: j-range [32wv, 32wv+32)
  const int lane = tid & 63;
  const int q    = lane >> 4;
  const int l16  = lane & 15;
  const int sm   = q >> 1;          // this lane finalizes s = sm
  const int b    = blockIdx.x;

  const float* Wg[4] = { w_ff1, w_ff2, w_ta, w_tb };

  // B operand = W_bot (k rows 128..255), n = g*128 + 32wv + 16s + l16
  half8 bW[4][2][4];                // [gate][s][kchunk]
#pragma unroll
  for (int g = 0; g < 4; ++g){
    const float* wp = Wg[g];
#pragma unroll
    for (int s = 0; s < 2; ++s){
      const int jc = 32*wv + 16*s + l16;
#pragma unroll
      for (int c = 0; c < 4; ++c)
#pragma unroll
        for (int i = 0; i < 8; ++i)
          bW[g][s][c][i] = (f16)wp[(128 + 32*c + 8*q + i)*Hh + jc];
    }
  }

  // zero hist ring (slot 15 must be 0 for t=0)
  ((float4*)hist)[tid] = make_float4(0.f, 0.f, 0.f, 0.f);

  f16* zg = zx + (size_t)b*Tt*512;
  const float4* zg4 = (const float4*)zg;         // chunk = 1024 float4

  // prologue: chunk0 -> regs -> zbuf[0]; chunk1 -> regs; dt chunk0 -> reg
  float4 rz[4];
#pragma unroll
  for (int j = 0; j < 4; ++j) rz[j] = zg4[j*256 + tid];
#pragma unroll
  for (int j = 0; j < 4; ++j) ((float4*)zbuf[0])[j*256 + tid] = rz[j];
#pragma unroll
  for (int j = 0; j < 4; ++j) rz[j] = zg4[1024 + j*256 + tid];
  float dtcur = dt[(size_t)b*Tt + l16] * 10.0f;
  __syncthreads();

  const f32x4 zero4 = {0.f, 0.f, 0.f, 0.f};
  const int zlane = (wv*16 + l16)*8;             // lane's b128 slot in a step row

  for (int c = 0; c < NCH; ++c){
    const int cur = c & 1, nxt = cur ^ 1;
#pragma unroll
    for (int j = 0; j < 4; ++j) ((float4*)zbuf[nxt])[j*256 + tid] = rz[j];
    if (c + 2 < NCH){
      const float4* src = zg4 + (size_t)(c+2)*1024;
#pragma unroll
      for (int j = 0; j < 4; ++j) rz[j] = src[j*256 + tid];
    }
    float dtnxt = dtcur;
    if (c + 1 < NCH) dtnxt = dt[(size_t)b*Tt + (c+1)*CH + l16] * 10.0f;
    const f16* zch = zbuf[cur];

#pragma unroll 4
    for (int st = 0; st < CH; ++st){
      const int slotR = (st + 15) & 15;
      // A operand: h broadcast (l16-independent), 4 x b128
      half8 af[4];
#pragma unroll
      for (int cc = 0; cc < 4; ++cc)
        af[cc] = *(const half8*)(&hist[slotR][32*cc + 8*q]);
      // z: one b128 per lane, holds (s,g) packed for n-cols of this lane
      half8 zv = *(const half8*)(zch + st*512 + zlane);
      const float dtt = rlane(dtcur, st);

      // 2+2 split K chains; only acc reg0 needed (M-rows duplicated)
      float R[4][2];
#pragma unroll
      for (int g = 0; g < 4; ++g)
#pragma unroll
        for (int s = 0; s < 2; ++s){
          f32x4 p = MFMA16(af[0], bW[g][s][0], zero4);
          p       = MFMA16(af[1], bW[g][s][1], p);
          f32x4 r2 = MFMA16(af[2], bW[g][s][2], zero4);
          r2       = MFMA16(af[3], bW[g][s][3], r2);
          R[g][s] = p[0] + r2[0];
        }
      // own-s select + z add + CfC cell (one per lane)
      float pre[4];
#pragma unroll
      for (int g = 0; g < 4; ++g){
        float rv = sm ? R[g][1] : R[g][0];
        f16  zz = sm ? zv[4+g] : zv[g];
        pre[g] = rv + (float)zz;
      }
      float u_ = fast_rcp(fast_ex2(L2E2*pre[0]) + 1.0f);   // (1-tanh)/2
      float v_ = fast_rcp(fast_ex2(L2E2*pre[1]) + 1.0f);
      float g_ = fast_rcp(fast_ex2(-L2E*(pre[2]*dtt + pre[3])) + 1.0f);
      float hn = 1.0f - 2.0f*(u_ - g_*(u_ - v_));
      if ((q & 1) == 0)                          // q=0 -> s=0, q=2 -> s=1
        hist[st][32*wv + 16*sm + l16] = (f16)hn;
      __syncthreads();
    }
    // dump h ring into consumed z region: h[t] -> zg[t*512 + 0..127]
    {
      const float4 hv = ((const float4*)hist)[tid];
      *(float4*)(zg + ((size_t)(c*CH + (tid >> 4)))*512 + (size_t)(tid & 15)*8) = hv;
    }
    __syncthreads();
    dtcur = dtnxt;
  }
}

// ---------------------------------------------------------------------------
// Head: out[tok] = h[tok] . head_w + head_b (h fp16 from dumped region).
// ---------------------------------------------------------------------------
__global__ __launch_bounds__(256, 4)
void head_k(const f16* __restrict__ zx, const float* __restrict__ head_w,
            const float* __restrict__ head_b, float* __restrict__ out)
{
  const int tok  = (blockIdx.x << 2) + (threadIdx.x >> 6);
  const int lane = threadIdx.x & 63;
  U1 cv; cv.u = *(const unsigned*)(zx + (size_t)tok*512 + 2*lane);
  float s = (float)cv.h[0]*head_w[2*lane] + (float)cv.h[1]*head_w[2*lane+1];
#pragma unroll
  for (int off = 32; off; off >>= 1) s += __shfl_xor(s, off);
  if (lane == 0) out[tok] = s + head_b[0];
}

extern "C" void kernel_launch(void* const* d_in, const int* in_sizes, int n_in,
                              void* d_out, int out_size, void* d_ws, size_t ws_size,
                              hipStream_t stream)
{
  const float* x       = (const float*)d_in[0];
  const float* dt      = (const float*)d_in[1];
  const float* ln_in_g = (const float*)d_in[2];
  const float* ln_in_b = (const float*)d_in[3];
  const float* proj_w  = (const float*)d_in[4];
  const float* proj_b  = (const float*)d_in[5];
  const float* ln_p_g  = (const float*)d_in[6];
  const float* ln_p_b  = (const float*)d_in[7];
  const float* ff1_w   = (const float*)d_in[8];
  const float* ff1_b   = (const float*)d_in[9];
  const float* ff2_w   = (const float*)d_in[10];
  const float* ff2_b   = (const float*)d_in[11];
  const float* ta_w    = (const float*)d_in[12];
  const float* ta_b    = (const float*)d_in[13];
  const float* tb_w    = (const float*)d_in[14];
  const float* tb_b    = (const float*)d_in[15];
  const float* head_w  = (const float*)d_in[16];
  const float* head_b  = (const float*)d_in[17];

  f16*   zx  = (f16*)d_ws;      // [b][t][512] fp16 = 256 MiB (z, then h)
  float* out = (float*)d_out;

  stage_a<<<dim3(256), dim3(512), 0, stream>>>(
      x, ln_in_g, ln_in_b, proj_w, proj_b, ln_p_g, ln_p_b,
      ff1_w, ff1_b, ff2_w, ff2_b, ta_w, ta_b, tb_w, tb_b, zx);

  scan_k<<<dim3(Bb), dim3(256), 0, stream>>>(
      zx, dt, ff1_w, ff2_w, ta_w, tb_w);

  head_k<<<dim3(Bb*Tt/4), dim3(256), 0, stream>>>(
      zx, head_w, head_b, out);
}